// Round 6
// baseline (416.586 us; speedup 1.0000x reference)
//
#include <hip/hip_runtime.h>
#include <hip/hip_bf16.h>
#include <math.h>

// Problem constants
#define B_  4
#define T_  8192
#define H_  1024
#define NHEAD 16
#define DH  64
#define BT  (B_*T_)   // 32768 rows

typedef __attribute__((ext_vector_type(8))) short bf16x8;
typedef __attribute__((ext_vector_type(4))) float f32x4;
typedef __attribute__((ext_vector_type(2))) float f32x2;
typedef __attribute__((ext_vector_type(2))) unsigned short u16x2;
typedef __attribute__((ext_vector_type(4))) unsigned short u16x4;
typedef __attribute__((ext_vector_type(8))) unsigned short u16x8;

static __device__ __forceinline__ float bf2f(unsigned short u) {
  union { unsigned int i; float f; } x; x.i = ((unsigned int)u) << 16; return x.f;
}
static __device__ __forceinline__ unsigned short f2bf(float f) {
  union { float f; unsigned int i; } x; x.f = f;
  unsigned int r = x.i + 0x7fffu + ((x.i >> 16) & 1u);  // RNE
  return (unsigned short)(r >> 16);
}

#define GL2LDS(gptr, sptr) \
  __builtin_amdgcn_global_load_lds((const __attribute__((address_space(1))) void*)(gptr), \
                                   (__attribute__((address_space(3))) void*)(sptr), 16, 0, 0)

#define BAR() do { asm volatile("" ::: "memory"); __builtin_amdgcn_s_barrier(); \
                   asm volatile("" ::: "memory"); } while (0)

// ---------------------------------------------------------------- cvt fp32->bf16
__global__ void cvt_kernel(const float* __restrict__ in, unsigned short* __restrict__ out, int n4) {
  int i = blockIdx.x * blockDim.x + threadIdx.x;
  int stride = gridDim.x * blockDim.x;
  for (int idx = i; idx < n4; idx += stride) {
    float4 v = reinterpret_cast<const float4*>(in)[idx];
    u16x4 o;
    o.x = f2bf(v.x); o.y = f2bf(v.y); o.z = f2bf(v.z); o.w = f2bf(v.w);
    reinterpret_cast<u16x4*>(out)[idx] = o;
  }
}

// ---------------------------------------------------------------- 256x256 bf16 GEMM, m201-style phases
// C[M,N] = A[M,K]*B[N,K]^T + bias ; M=32768, N=K=1024. BM=BN=256, BK=64,
// 8 waves (2M x 4N), per-wave 128x64 out. LDS 128 KiB = 2 K-tile buffers.
// SWIZZLE: full-depth XOR byte ^= ((row&7)<<4); linear gload_lds dest +
// pre-swizzled global SOURCE + XOR'd read col (verified r5: conflicts = 0).
// PHASES (r6, m201 template): each phase = {ds_read subtile + stage issue ->
// BAR -> lgkmcnt(0)+sched_barrier -> setprio 16xMFMA setprio -> BAR}.
// Reads/phase: P1=12 (A rh0 + B ch0), P2=4 (B ch1), P3=8 (A rh1), P4=0.
// MFMA order: (0,0)(0,1)(1,1)(1,0) so each phase reuses freshest B regs.
// LIVENESS (proven r4/r5): B region last read P2 -> restage P3 (all waves'
// P2 reads complete before B2-of-P2 releases); A last read P3 -> restage P4.
// vmcnt(8) at end-P4 drains tile t+1 (t+2's 8 stay in flight). Tail: t=14
// waits vmcnt(0) (only tile15's 8 outstanding); t=15 no stage/wait.
// grid = 512 blocks, XCD-bijective swizzle (512%8==0).
__global__ __launch_bounds__(512, 2) void gemm256(
    const unsigned short* __restrict__ A,
    const unsigned short* __restrict__ Bm,
    const float* __restrict__ bias,
    unsigned short* __restrict__ C) {
  const int K = 1024, N = 1024;
  __shared__ char lds[131072];
  const int tid = threadIdx.x, lane = tid & 63, wid = tid >> 6;
  const int orig = blockIdx.x;
  const int swzb = (orig & 7) * 64 + (orig >> 3);
  const int bm = (swzb >> 2) * 256, bn = (swzb & 3) * 256;
  const int wm = wid >> 2, wn = wid & 3;

  // staging: lane covers linear LDS bytes (wid*1024 + lane*16) of a 64-row
  // chunk = row sr, swizzled source col.
  const int sr   = wid * 8 + (lane >> 3);
  const int scol = ((lane & 7) * 8) ^ ((lane >> 3) << 3);
  const unsigned short* gA = A  + (size_t)(bm + sr) * K + scol;
  const unsigned short* gB = Bm + (size_t)(bn + sr) * K + scol;
  const int dstw = wid * 1024;

  // fragment read: col = ((lane>>4)*16 + ks*64) ^ ((lane&7)<<4)
  const int aswz  = (lane & 7) << 4;
  const int arow0 = (wm * 128 + (lane & 15)) * 128;            // A row-base bytes
  const int brow0 = 32768 + (wn * 64 + (lane & 15)) * 128;     // B row-base bytes

  f32x4 acc[8][4];
#pragma unroll
  for (int fn = 0; fn < 4; ++fn) {
    float bv = bias[bn + wn * 64 + fn * 16 + (lane & 15)];
    f32x4 sp = {bv, bv, bv, bv};
#pragma unroll
    for (int fm = 0; fm < 8; ++fm) acc[fm][fn] = sp;
  }

  bf16x8 aF[4][2], bF[4][2];

  auto stA4 = [&](int buf, int kt) {                 // full A tile: 4 gloads
    char* d = lds + buf * 65536 + dstw;
    const unsigned short* g = gA + kt * 64;
    GL2LDS(g, d);
    GL2LDS(g + (size_t)64  * K, d + 8192);
    GL2LDS(g + (size_t)128 * K, d + 16384);
    GL2LDS(g + (size_t)192 * K, d + 24576);
  };
  auto stB = [&](int buf, int kt) {                  // full B tile: 4 gloads
    char* d = lds + buf * 65536 + 32768 + dstw;
    const unsigned short* g = gB + kt * 64;
    GL2LDS(g, d);
    GL2LDS(g + (size_t)64  * K, d + 8192);
    GL2LDS(g + (size_t)128 * K, d + 16384);
    GL2LDS(g + (size_t)192 * K, d + 24576);
  };
  auto loadA = [&](int buf, int mh) {
#pragma unroll
    for (int f = 0; f < 4; ++f)
#pragma unroll
      for (int ks = 0; ks < 2; ++ks)
        aF[f][ks] = *(const bf16x8*)(lds + buf * 65536 + arow0 + (mh * 4 + f) * 2048
                                     + (((lane >> 4) * 16 + ks * 64) ^ aswz));
  };
  auto loadB = [&](int buf, int nh) {
#pragma unroll
    for (int f = 0; f < 2; ++f)
#pragma unroll
      for (int ks = 0; ks < 2; ++ks)
        bF[nh * 2 + f][ks] = *(const bf16x8*)(lds + buf * 65536 + brow0 + (nh * 2 + f) * 2048
                                              + (((lane >> 4) * 16 + ks * 64) ^ aswz));
  };
  auto quad = [&](int mh, int nh) {                  // 16 MFMA cluster (T5 setprio)
    __builtin_amdgcn_s_setprio(1);
#pragma unroll
    for (int f = 0; f < 4; ++f)
#pragma unroll
      for (int g2 = 0; g2 < 2; ++g2)
#pragma unroll
        for (int ks = 0; ks < 2; ++ks)
          acc[mh * 4 + f][nh * 2 + g2] = __builtin_amdgcn_mfma_f32_16x16x32_bf16(
              aF[f][ks], bF[nh * 2 + g2][ks], acc[mh * 4 + f][nh * 2 + g2], 0, 0, 0);
    __builtin_amdgcn_s_setprio(0);
  };

  // prologue: stage K-tiles 0 and 1 (tile0's 8 issues precede tile1's 8)
  stA4(0, 0); stB(0, 0);
  stA4(1, 1); stB(1, 1);
  asm volatile("s_waitcnt vmcnt(8)" ::: "memory");   // K-tile 0 fully landed
  BAR();

#define LGKM0() do { asm volatile("s_waitcnt lgkmcnt(0)" ::: "memory"); \
                     __builtin_amdgcn_sched_barrier(0); } while (0)

#define KTILE(t, STG, WSTR, DOW)                              \
  {                                                           \
    const int b_ = (t) & 1;                                   \
    /* P1: A(rh0) 8 + B(ch0) 4 reads */                       \
    loadA(b_, 0); loadB(b_, 0);                               \
    asm volatile("s_waitcnt lgkmcnt(8)" ::: "memory");        \
    BAR();                                                    \
    LGKM0();                                                  \
    quad(0, 0);                                               \
    BAR();                                                    \
    /* P2: B(ch1) 4 reads */                                  \
    loadB(b_, 1);                                             \
    BAR();                                                    \
    LGKM0();                                                  \
    quad(0, 1);                                               \
    BAR();                                                    \
    /* P3: A(rh1) 8 reads + B restage (B last read P2) */     \
    loadA(b_, 1);                                             \
    if (STG) stB(b_, (t) + 2);                                \
    BAR();                                                    \
    LGKM0();                                                  \
    quad(1, 1);                                               \
    BAR();                                                    \
    /* P4: 0 reads + A restage (A last read P3) */            \
    if (STG) stA4(b_, (t) + 2);                               \
    BAR();                                                    \
    quad(1, 0);                                               \
    if (DOW) { asm volatile("s_waitcnt vmcnt(" WSTR ")" ::: "memory"); } \
    BAR();                                                    \
  }

  for (int t = 0; t < 14; ++t) KTILE(t, 1, "8", 1)
  KTILE(14, 0, "0", 1)
  KTILE(15, 0, "0", 0)
#undef KTILE
#undef LGKM0

  // epilogue: C write
  const int crow0 = bm + wm * 128 + (lane >> 4) * 4;
  const int ccol0 = bn + wn * 64 + (lane & 15);
#pragma unroll
  for (int fm = 0; fm < 8; ++fm)
#pragma unroll
    for (int j = 0; j < 4; ++j) {
      unsigned short* cp = C + (size_t)(crow0 + fm * 16 + j) * N + ccol0;
#pragma unroll
      for (int fn = 0; fn < 4; ++fn) cp[fn * 16] = f2bf(acc[fm][fn][j]);
    }
}

// ---------------------------------------------------------------- phase1 (MFMA): U-partials + colsum
__global__ __launch_bounds__(256, 2) void phase1(
    const unsigned short* __restrict__ Pk,
    const unsigned short* __restrict__ Pv,
    const float* __restrict__ mask_attn,
    float* __restrict__ Upart,     // [8][64][64][64]
    float* __restrict__ cspart) {  // [8][64][64]
  const int chunk = blockIdx.x;
  const int nh = blockIdx.y;
  const int n = nh >> 4, h = nh & 15;
  const int tid = threadIdx.x, lane = tid & 63, wid = tid >> 6;
  __shared__ __align__(16) unsigned short ekT[64 * 256];  // 32 KB
  __shared__ __align__(16) unsigned short vpT[64 * 256];  // 32 KB

  f32x4 acc[5];
#pragma unroll
  for (int i = 0; i < 5; ++i) acc[i] = (f32x4){0.f, 0.f, 0.f, 0.f};
  bf16x8 ones;
#pragma unroll
  for (int j = 0; j < 8; ++j) ones[j] = (short)0x3f80;

  const int isV = tid >> 7;
  const int slot0 = tid & 127;
  const unsigned short* src = isV ? Pv : Pk;
  unsigned short* dstT = isV ? vpT : ekT;

  const int arow = wid * 16 + (lane & 15);
  const int aswz = ((arow & 7) ^ ((arow >> 3) & 7)) << 4;

  for (int stage = 0; stage < 4; ++stage) {
    if (stage) __syncthreads();
#pragma unroll
    for (int r = 0; r < 2; ++r) {
      const int slot = slot0 + r * 128;
      const int toct = slot >> 3;
      const int d0   = (slot & 7) * 8;
      const int tbase = chunk * 1024 + stage * 256 + toct * 8;
      u16x8 in[8];
#pragma unroll
      for (int s = 0; s < 8; ++s)
        in[s] = *(const u16x8*)(src + (size_t)(n * T_ + tbase + s) * H_ + h * DH + d0);
      if (!isV) {
#pragma unroll
        for (int s = 0; s < 8; ++s) {
          const float madd = -10000.f * (1.f - mask_attn[n * T_ + tbase + s]);
          u16x8 o;
#pragma unroll
          for (int j = 0; j < 8; ++j) o[j] = f2bf(__expf(bf2f(in[s][j]) + madd));
          in[s] = o;
        }
      }
#pragma unroll
      for (int i = 0; i < 8; ++i) {
        u16x8 o;
#pragma unroll
        for (int s = 0; s < 8; ++s) o[s] = in[s][i];
        const int d = d0 + i;
        const int boff = (toct * 16) ^ (((d & 7) ^ ((d >> 3) & 7)) << 4);
        *(u16x8*)((char*)dstT + d * 512 + boff) = o;
      }
    }
    __syncthreads();
#pragma unroll
    for (int kk = 0; kk < 8; ++kk) {
      const int koff = kk * 64 + (lane >> 4) * 16;
      bf16x8 af = *(const bf16x8*)((const char*)ekT + arow * 512 + (koff ^ aswz));
      acc[4] = __builtin_amdgcn_mfma_f32_16x16x32_bf16(af, ones, acc[4], 0, 0, 0);
#pragma unroll
      for (int nn = 0; nn < 4; ++nn) {
        const int brow = nn * 16 + (lane & 15);
        const int bswz = ((brow & 7) ^ ((brow >> 3) & 7)) << 4;
        bf16x8 bf_ = *(const bf16x8*)((const char*)vpT + brow * 512 + (koff ^ bswz));
        acc[nn] = __builtin_amdgcn_mfma_f32_16x16x32_bf16(af, bf_, acc[nn], 0, 0, 0);
      }
    }
  }

  const int d = wid * 16 + (lane >> 4) * 4;
  const int e = lane & 15;
  float* up = Upart + ((size_t)(chunk * 64 + nh) * 64) * 64;
#pragma unroll
  for (int nn = 0; nn < 4; ++nn)
#pragma unroll
    for (int j = 0; j < 4; ++j)
      up[(size_t)(d + j) * 64 + nn * 16 + e] = acc[nn][j];
  if (e == 0)
#pragma unroll
    for (int j = 0; j < 4; ++j)
      cspart[((size_t)chunk * 64 + nh) * 64 + d + j] = acc[4][j];
}

// ---------------------------------------------------------------- ctx build
__global__ void ctxbuild(const float* __restrict__ Upart,
                         const float* __restrict__ cspart,
                         unsigned short* __restrict__ ctxT) {  // [64 nh][64 e][64 d]
  const int nh = blockIdx.x, tid = threadIdx.x;
  __shared__ float cs[64];
  if (tid < 64) {
    float s = 0;
    for (int c = 0; c < 8; ++c) s += cspart[((size_t)c * 64 + nh) * 64 + tid];
    cs[tid] = s;
  }
  __syncthreads();
  const int d0 = (tid >> 4) * 4, e0 = (tid & 15) * 4;
#pragma unroll
  for (int i = 0; i < 4; ++i) {
    const float inv = 0.125f / cs[d0 + i];   // 1/(sqrt(64)*colsum)
#pragma unroll
    for (int j = 0; j < 4; ++j) {
      float s = 0;
      for (int c = 0; c < 8; ++c)
        s += Upart[((size_t)(c * 64 + nh) * 64 + d0 + i) * 64 + e0 + j];
      ctxT[((size_t)nh * 64 + (e0 + j)) * 64 + (d0 + i)] = f2bf(s * inv);
    }
  }
}

// ---------------------------------------------------------------- out: softmax_feat(qp) @ ctx
__global__ __launch_bounds__(256) void outk(
    const unsigned short* __restrict__ Pq,
    const unsigned short* __restrict__ ctxT,
    float* __restrict__ Out) {
  const int tb = blockIdx.x;
  const int nh = blockIdx.y;
  const int n = nh >> 4, h = nh & 15;
  const int tid = threadIdx.x, lane = tid & 63, wid = tid >> 6;
  __shared__ unsigned short sp[128][72];

  bf16x8 breg[2][4];
#pragma unroll
  for (int ks = 0; ks < 2; ++ks)
#pragma unroll
    for (int nn = 0; nn < 4; ++nn)
      breg[ks][nn] = *(const bf16x8*)(ctxT + ((size_t)nh * 64 + nn * 16 + (lane & 15)) * 64
                                      + ks * 32 + (lane >> 4) * 8);

  const int r = tid >> 1, half = tid & 1;
  const int t0 = tb * 128;
  const size_t qoff = (size_t)(n * T_ + t0 + r) * H_ + h * DH + half * 32;
  u16x8 qv[4];
#pragma unroll
  for (int s = 0; s < 4; ++s) qv[s] = *(const u16x8*)(Pq + qoff + s * 8);
  float e[32]; float sum = 0.f;
#pragma unroll
  for (int s = 0; s < 4; ++s)
#pragma unroll
    for (int j = 0; j < 8; ++j) { float x = __expf(bf2f(qv[s][j])); e[s * 8 + j] = x; sum += x; }
  sum += __shfl_xor(sum, 1);
  const float inv = 1.f / sum;
#pragma unroll
  for (int s = 0; s < 4; ++s) {
    u16x8 pb;
#pragma unroll
    for (int j = 0; j < 8; ++j) pb[j] = f2bf(e[s * 8 + j] * inv);
    *(u16x8*)&sp[r][half * 32 + s * 8] = pb;
  }
  __syncthreads();

  f32x4 acc[2][4];
  f32x4 z = {0.f, 0.f, 0.f, 0.f};
#pragma unroll
  for (int mm = 0; mm < 2; ++mm)
#pragma unroll
    for (int nn = 0; nn < 4; ++nn) acc[mm][nn] = z;
  const int wm = wid * 32;
#pragma unroll
  for (int ks = 0; ks < 2; ++ks) {
    bf16x8 av[2];
#pragma unroll
    for (int mm = 0; mm < 2; ++mm)
      av[mm] = *(const bf16x8*)((const char*)&sp[0][0]
               + (wm + mm * 16 + (lane & 15)) * 144 + ks * 64 + (lane >> 4) * 16);
#pragma unroll
    for (int mm = 0; mm < 2; ++mm)
#pragma unroll
      for (int nn = 0; nn < 4; ++nn)
        acc[mm][nn] = __builtin_amdgcn_mfma_f32_16x16x32_bf16(av[mm], breg[ks][nn], acc[mm][nn], 0, 0, 0);
  }

#pragma unroll
  for (int mm = 0; mm < 2; ++mm)
#pragma unroll
    for (int j = 0; j < 4; ++j) {
      const int row = t0 + wm + mm * 16 + (lane >> 4) * 4 + j;
      float* op = Out + ((size_t)n * T_ + row) * H_ + h * DH + (lane & 15);
#pragma unroll
      for (int nn = 0; nn < 4; ++nn) op[nn * 16] = acc[mm][nn][j];
    }
}

// ---------------------------------------------------------------- launch
extern "C" void kernel_launch(void* const* d_in, const int* in_sizes, int n_in,
                              void* d_out, int out_size, void* d_ws, size_t ws_size,
                              hipStream_t stream) {
  const float* q  = (const float*)d_in[0];
  const float* k  = (const float*)d_in[1];
  const float* v  = (const float*)d_in[2];
  // d_in[3] = mask_q: per-row constant before feature-dim softmax -> provably a no-op
  const float* mask_attn = (const float*)d_in[4];
  const float* Wq = (const float*)d_in[5];
  const float* bq = (const float*)d_in[6];
  const float* Wk = (const float*)d_in[7];
  const float* bk = (const float*)d_in[8];
  const float* Wv = (const float*)d_in[9];
  const float* bv = (const float*)d_in[10];
  float* out = (float*)d_out;

  char* ws = (char*)d_ws;
  size_t off = 0;
  unsigned short* Xb = (unsigned short*)(ws + off); off += (size_t)BT * H_ * 2;       // 64 MB
  unsigned short* Wb = (unsigned short*)(ws + off); off += (size_t)3 * H_ * H_ * 2;   // 6 MB
  unsigned short* Pq = (unsigned short*)(ws + off); off += (size_t)BT * H_ * 2;
  unsigned short* Pk = (unsigned short*)(ws + off); off += (size_t)BT * H_ * 2;
  unsigned short* Pv = (unsigned short*)(ws + off); off += (size_t)BT * H_ * 2;
  float* Upart  = (float*)(ws + off); off += (size_t)8 * 64 * 64 * 64 * 4;            // 8 MB
  float* cspart = (float*)(ws + off); off += (size_t)8 * 64 * 64 * 4;
  unsigned short* ctxT = (unsigned short*)(ws + off); off += (size_t)64 * 64 * 64 * 2;

  dim3 blk(256);
  const int nW4 = H_ * H_ / 4;
  cvt_kernel<<<dim3(512), blk, 0, stream>>>(Wq, Wb + 0 * H_ * H_, nW4);
  cvt_kernel<<<dim3(512), blk, 0, stream>>>(Wk, Wb + 1 * H_ * H_, nW4);
  cvt_kernel<<<dim3(512), blk, 0, stream>>>(Wv, Wb + 2 * H_ * H_, nW4);

  const int nX4 = BT * H_ / 4;
  dim3 gblk(512);
  dim3 ggrid(512);   // 128 Mtiles x 4 Ntiles
  cvt_kernel<<<dim3(2048), blk, 0, stream>>>(k, Xb, nX4);
  gemm256<<<ggrid, gblk, 0, stream>>>(Xb, Wb + 1 * H_ * H_, bk, Pk);
  cvt_kernel<<<dim3(2048), blk, 0, stream>>>(v, Xb, nX4);
  gemm256<<<ggrid, gblk, 0, stream>>>(Xb, Wb + 2 * H_ * H_, bv, Pv);
  cvt_kernel<<<dim3(2048), blk, 0, stream>>>(q, Xb, nX4);
  gemm256<<<ggrid, gblk, 0, stream>>>(Xb, Wb + 0 * H_ * H_, bq, Pq);

  phase1<<<dim3(8, 64), blk, 0, stream>>>(Pk, Pv, mask_attn, Upart, cspart);
  ctxbuild<<<dim3(64), blk, 0, stream>>>(Upart, cspart, ctxT);
  outk<<<dim3(64, 64), blk, 0, stream>>>(Pq, ctxT, out);
}

// Round 7
// 404.709 us; speedup vs baseline: 1.0293x; 1.0293x over previous
//
#include <hip/hip_runtime.h>
#include <hip/hip_bf16.h>
#include <math.h>

// Problem constants
#define B_  4
#define T_  8192
#define H_  1024
#define NHEAD 16
#define DH  64
#define BT  (B_*T_)   // 32768 rows

typedef __attribute__((ext_vector_type(8))) short bf16x8;
typedef __attribute__((ext_vector_type(4))) float f32x4;
typedef __attribute__((ext_vector_type(2))) float f32x2;
typedef __attribute__((ext_vector_type(2))) unsigned short u16x2;
typedef __attribute__((ext_vector_type(4))) unsigned short u16x4;
typedef __attribute__((ext_vector_type(8))) unsigned short u16x8;

static __device__ __forceinline__ float bf2f(unsigned short u) {
  union { unsigned int i; float f; } x; x.i = ((unsigned int)u) << 16; return x.f;
}
static __device__ __forceinline__ unsigned short f2bf(float f) {
  union { float f; unsigned int i; } x; x.f = f;
  unsigned int r = x.i + 0x7fffu + ((x.i >> 16) & 1u);  // RNE
  return (unsigned short)(r >> 16);
}

#define GL2LDS(gptr, sptr) \
  __builtin_amdgcn_global_load_lds((const __attribute__((address_space(1))) void*)(gptr), \
                                   (__attribute__((address_space(3))) void*)(sptr), 16, 0, 0)

#define BAR() do { asm volatile("" ::: "memory"); __builtin_amdgcn_s_barrier(); \
                   asm volatile("" ::: "memory"); } while (0)

// ---------------------------------------------------------------- cvt fp32->bf16 (weights only now)
__global__ void cvt_kernel(const float* __restrict__ in, unsigned short* __restrict__ out, int n4) {
  int i = blockIdx.x * blockDim.x + threadIdx.x;
  int stride = gridDim.x * blockDim.x;
  for (int idx = i; idx < n4; idx += stride) {
    float4 v = reinterpret_cast<const float4*>(in)[idx];
    u16x4 o;
    o.x = f2bf(v.x); o.y = f2bf(v.y); o.z = f2bf(v.z); o.w = f2bf(v.w);
    reinterpret_cast<u16x4*>(out)[idx] = o;
  }
}

// ---------------------------------------------------------------- 256x256 bf16 GEMM, fused fp32->bf16 A-staging
// C[M,N] = cvt(A_f32)[M,K]*B[N,K]^T + bias ; M=32768, N=K=1024. BM=BN=256,
// BK=64, 8 waves (2M x 4N). LDS 128 KiB = 2 K-tile buffers (A 32KB + B 32KB).
// A: fp32 from HBM, reg-staged (T14): issue 8x dwordx4 at P1, vmcnt+cvt+
// 4x ds_write_b128 at P4 (writes go to the swizzled layout directly).
// B: bf16 weights via gload_lds, pre-swizzled source (r5-verified, 0 conflicts).
// SWIZZLE both sides: byte ^= ((row&7)<<4). K-loop = r5 structure (best: 81us).
// LIVENESS/vmcnt (re-derived): tile t P1 issues A32(t+2) regs(8); P3 issues
// B(t+2) gload_lds(4); P4 vmcnt(4) drains [B(t+1) + A32(t+2)] leaving B(t+2)
// -> writeA(t+2) into buf(t&1) (A last read P3, barrier covers other waves)
// -> quad(1,1) -> lgkmcnt(0) -> BAR. Tail: t=14 vmcnt(0) drains B(15).
// grid = 512 blocks, XCD-bijective swizzle (512%8==0).
__global__ __launch_bounds__(512, 2) void gemm256(
    const float* __restrict__ A,
    const unsigned short* __restrict__ Bm,
    const float* __restrict__ bias,
    unsigned short* __restrict__ C) {
  const int K = 1024, N = 1024;
  __shared__ char lds[131072];
  const int tid = threadIdx.x, lane = tid & 63, wid = tid >> 6;
  const int orig = blockIdx.x;
  const int swzb = (orig & 7) * 64 + (orig >> 3);
  const int bm = (swzb >> 2) * 256, bn = (swzb & 3) * 256;
  const int wm = wid >> 2, wn = wid & 3;

  // ---- A fp32 reg-staging geometry: thread covers 8 floats of row asr in
  // each of 4 row-slots; ds_write goes to the swizzled byte address.
  const int asr = wid * 8 + (lane >> 3);          // row 0..63 within slot
  const int ac0 = (lane & 7) * 8;                 // fp32 col within K-tile
  const float* gA32 = A + (size_t)(bm + asr) * K + ac0;
  const int awr = asr * 128 + (((lane & 7) * 16) ^ ((asr & 7) << 4));

  // ---- B staging (gload_lds, pre-swizzled source)
  const int sr   = wid * 8 + (lane >> 3);
  const int scol = ((lane & 7) * 8) ^ ((lane >> 3) << 3);
  const unsigned short* gB = Bm + (size_t)(bn + sr) * K + scol;
  const int dstw = wid * 1024;

  // fragment read: col = ((lane>>4)*16 + ks*64) ^ ((lane&7)<<4)
  const int aswz  = (lane & 7) << 4;
  const int arow0 = (wm * 128 + (lane & 15)) * 128;            // A row-base bytes
  const int brow0 = 32768 + (wn * 64 + (lane & 15)) * 128;     // B row-base bytes

  f32x4 acc[8][4];
#pragma unroll
  for (int fn = 0; fn < 4; ++fn) {
    float bv = bias[bn + wn * 64 + fn * 16 + (lane & 15)];
    f32x4 sp = {bv, bv, bv, bv};
#pragma unroll
    for (int fm = 0; fm < 8; ++fm) acc[fm][fn] = sp;
  }

  bf16x8 aF[4][2], bF[4][2];
  f32x4 ar[4][2];   // in-flight A fp32 (32 VGPRs)

  auto issueA32 = [&](int kt) {
#pragma unroll
    for (int s = 0; s < 4; ++s) {
      const float* g = gA32 + (size_t)(s * 64) * K + kt * 64;
      ar[s][0] = *(const f32x4*)(g);
      ar[s][1] = *(const f32x4*)(g + 4);
    }
  };
  auto writeA = [&](int buf) {
#pragma unroll
    for (int s = 0; s < 4; ++s) {
      u16x8 o;
#pragma unroll
      for (int j = 0; j < 4; ++j) { o[j] = (short)f2bf(ar[s][0][j]); o[4 + j] = (short)f2bf(ar[s][1][j]); }
      *(u16x8*)(lds + buf * 65536 + s * 8192 + awr) = o;
    }
  };
  auto stB = [&](int buf, int kt) {                  // full B tile: 4 gloads
    char* d = lds + buf * 65536 + 32768 + dstw;
    const unsigned short* g = gB + kt * 64;
    GL2LDS(g, d);
    GL2LDS(g + (size_t)64  * K, d + 8192);
    GL2LDS(g + (size_t)128 * K, d + 16384);
    GL2LDS(g + (size_t)192 * K, d + 24576);
  };
  auto loadA = [&](int buf, int mh) {
#pragma unroll
    for (int f = 0; f < 4; ++f)
#pragma unroll
      for (int ks = 0; ks < 2; ++ks)
        aF[f][ks] = *(const bf16x8*)(lds + buf * 65536 + arow0 + (mh * 4 + f) * 2048
                                     + (((lane >> 4) * 16 + ks * 64) ^ aswz));
  };
  auto loadB = [&](int buf, int nh) {
#pragma unroll
    for (int f = 0; f < 2; ++f)
#pragma unroll
      for (int ks = 0; ks < 2; ++ks)
        bF[nh * 2 + f][ks] = *(const bf16x8*)(lds + buf * 65536 + brow0 + (nh * 2 + f) * 2048
                                              + (((lane >> 4) * 16 + ks * 64) ^ aswz));
  };
  auto quad = [&](int mh, int nh) {                  // 16 MFMA cluster (T5 setprio)
    __builtin_amdgcn_s_setprio(1);
#pragma unroll
    for (int f = 0; f < 4; ++f)
#pragma unroll
      for (int g2 = 0; g2 < 2; ++g2)
#pragma unroll
        for (int ks = 0; ks < 2; ++ks)
          acc[mh * 4 + f][nh * 2 + g2] = __builtin_amdgcn_mfma_f32_16x16x32_bf16(
              aF[f][ks], bF[nh * 2 + g2][ks], acc[mh * 4 + f][nh * 2 + g2], 0, 0, 0);
    __builtin_amdgcn_s_setprio(0);
  };

  // prologue: tiles 0 and 1
  issueA32(0);
  asm volatile("s_waitcnt vmcnt(0)" ::: "memory");   // A32(0) (+bias) landed
  writeA(0);
  issueA32(1);
  stB(0, 0); stB(1, 1);                              // 8 gload_lds after A32(1)'s 8
  asm volatile("s_waitcnt vmcnt(8)" ::: "memory");   // drains A32(1)
  writeA(1);
  asm volatile("s_waitcnt lgkmcnt(0)" ::: "memory"); // A writes visible
  asm volatile("s_waitcnt vmcnt(4)" ::: "memory");   // drains B(0); B(1) in flight
  BAR();

#define KTILE(t, STG, WSTR, DOW)                              \
  {                                                           \
    const int b_ = (t) & 1;                                   \
    if (STG) issueA32((t) + 2);                               \
    loadA(b_, 0); loadB(b_, 0);                               \
    quad(0, 0);                                               \
    BAR();                                                    \
    loadB(b_, 1);                                             \
    quad(0, 1);                                               \
    BAR();                                                    \
    if (STG) stB(b_, (t) + 2);                                \
    loadA(b_, 1);                                             \
    quad(1, 0);                                               \
    BAR();                                                    \
    if (DOW) { asm volatile("s_waitcnt vmcnt(" WSTR ")" ::: "memory"); } \
    if (STG) writeA(b_);                                      \
    quad(1, 1);                                               \
    asm volatile("s_waitcnt lgkmcnt(0)" ::: "memory");        \
    BAR();                                                    \
  }

  for (int t = 0; t < 14; ++t) KTILE(t, 1, "4", 1)
  KTILE(14, 0, "0", 1)
  KTILE(15, 0, "0", 0)
#undef KTILE

  // epilogue: C write
  const int crow0 = bm + wm * 128 + (lane >> 4) * 4;
  const int ccol0 = bn + wn * 64 + (lane & 15);
#pragma unroll
  for (int fm = 0; fm < 8; ++fm)
#pragma unroll
    for (int j = 0; j < 4; ++j) {
      unsigned short* cp = C + (size_t)(crow0 + fm * 16 + j) * N + ccol0;
#pragma unroll
      for (int fn = 0; fn < 4; ++fn) cp[fn * 16] = f2bf(acc[fm][fn][j]);
    }
}

// ---------------------------------------------------------------- phase1 (MFMA): U-partials + colsum
__global__ __launch_bounds__(256, 2) void phase1(
    const unsigned short* __restrict__ Pk,
    const unsigned short* __restrict__ Pv,
    const float* __restrict__ mask_attn,
    float* __restrict__ Upart,     // [8][64][64][64]
    float* __restrict__ cspart) {  // [8][64][64]
  const int chunk = blockIdx.x;
  const int nh = blockIdx.y;
  const int n = nh >> 4, h = nh & 15;
  const int tid = threadIdx.x, lane = tid & 63, wid = tid >> 6;
  __shared__ __align__(16) unsigned short ekT[64 * 256];  // 32 KB
  __shared__ __align__(16) unsigned short vpT[64 * 256];  // 32 KB

  f32x4 acc[5];
#pragma unroll
  for (int i = 0; i < 5; ++i) acc[i] = (f32x4){0.f, 0.f, 0.f, 0.f};
  bf16x8 ones;
#pragma unroll
  for (int j = 0; j < 8; ++j) ones[j] = (short)0x3f80;

  const int isV = tid >> 7;
  const int slot0 = tid & 127;
  const unsigned short* src = isV ? Pv : Pk;
  unsigned short* dstT = isV ? vpT : ekT;

  const int arow = wid * 16 + (lane & 15);
  const int aswz = ((arow & 7) ^ ((arow >> 3) & 7)) << 4;

  for (int stage = 0; stage < 4; ++stage) {
    if (stage) __syncthreads();
#pragma unroll
    for (int r = 0; r < 2; ++r) {
      const int slot = slot0 + r * 128;
      const int toct = slot >> 3;
      const int d0   = (slot & 7) * 8;
      const int tbase = chunk * 1024 + stage * 256 + toct * 8;
      u16x8 in[8];
#pragma unroll
      for (int s = 0; s < 8; ++s)
        in[s] = *(const u16x8*)(src + (size_t)(n * T_ + tbase + s) * H_ + h * DH + d0);
      if (!isV) {
#pragma unroll
        for (int s = 0; s < 8; ++s) {
          const float madd = -10000.f * (1.f - mask_attn[n * T_ + tbase + s]);
          u16x8 o;
#pragma unroll
          for (int j = 0; j < 8; ++j) o[j] = f2bf(__expf(bf2f(in[s][j]) + madd));
          in[s] = o;
        }
      }
#pragma unroll
      for (int i = 0; i < 8; ++i) {
        u16x8 o;
#pragma unroll
        for (int s = 0; s < 8; ++s) o[s] = in[s][i];
        const int d = d0 + i;
        const int boff = (toct * 16) ^ (((d & 7) ^ ((d >> 3) & 7)) << 4);
        *(u16x8*)((char*)dstT + d * 512 + boff) = o;
      }
    }
    __syncthreads();
#pragma unroll
    for (int kk = 0; kk < 8; ++kk) {
      const int koff = kk * 64 + (lane >> 4) * 16;
      bf16x8 af = *(const bf16x8*)((const char*)ekT + arow * 512 + (koff ^ aswz));
      acc[4] = __builtin_amdgcn_mfma_f32_16x16x32_bf16(af, ones, acc[4], 0, 0, 0);
#pragma unroll
      for (int nn = 0; nn < 4; ++nn) {
        const int brow = nn * 16 + (lane & 15);
        const int bswz = ((brow & 7) ^ ((brow >> 3) & 7)) << 4;
        bf16x8 bf_ = *(const bf16x8*)((const char*)vpT + brow * 512 + (koff ^ bswz));
        acc[nn] = __builtin_amdgcn_mfma_f32_16x16x32_bf16(af, bf_, acc[nn], 0, 0, 0);
      }
    }
  }

  const int d = wid * 16 + (lane >> 4) * 4;
  const int e = lane & 15;
  float* up = Upart + ((size_t)(chunk * 64 + nh) * 64) * 64;
#pragma unroll
  for (int nn = 0; nn < 4; ++nn)
#pragma unroll
    for (int j = 0; j < 4; ++j)
      up[(size_t)(d + j) * 64 + nn * 16 + e] = acc[nn][j];
  if (e == 0)
#pragma unroll
    for (int j = 0; j < 4; ++j)
      cspart[((size_t)chunk * 64 + nh) * 64 + d + j] = acc[4][j];
}

// ---------------------------------------------------------------- ctx build
__global__ void ctxbuild(const float* __restrict__ Upart,
                         const float* __restrict__ cspart,
                         unsigned short* __restrict__ ctxT) {  // [64 nh][64 e][64 d]
  const int nh = blockIdx.x, tid = threadIdx.x;
  __shared__ float cs[64];
  if (tid < 64) {
    float s = 0;
    for (int c = 0; c < 8; ++c) s += cspart[((size_t)c * 64 + nh) * 64 + tid];
    cs[tid] = s;
  }
  __syncthreads();
  const int d0 = (tid >> 4) * 4, e0 = (tid & 15) * 4;
#pragma unroll
  for (int i = 0; i < 4; ++i) {
    const float inv = 0.125f / cs[d0 + i];   // 1/(sqrt(64)*colsum)
#pragma unroll
    for (int j = 0; j < 4; ++j) {
      float s = 0;
      for (int c = 0; c < 8; ++c)
        s += Upart[((size_t)(c * 64 + nh) * 64 + d0 + i) * 64 + e0 + j];
      ctxT[((size_t)nh * 64 + (e0 + j)) * 64 + (d0 + i)] = f2bf(s * inv);
    }
  }
}

// ---------------------------------------------------------------- out: softmax_feat(qp) @ ctx
__global__ __launch_bounds__(256) void outk(
    const unsigned short* __restrict__ Pq,
    const unsigned short* __restrict__ ctxT,
    float* __restrict__ Out) {
  const int tb = blockIdx.x;
  const int nh = blockIdx.y;
  const int n = nh >> 4, h = nh & 15;
  const int tid = threadIdx.x, lane = tid & 63, wid = tid >> 6;
  __shared__ unsigned short sp[128][72];

  bf16x8 breg[2][4];
#pragma unroll
  for (int ks = 0; ks < 2; ++ks)
#pragma unroll
    for (int nn = 0; nn < 4; ++nn)
      breg[ks][nn] = *(const bf16x8*)(ctxT + ((size_t)nh * 64 + nn * 16 + (lane & 15)) * 64
                                      + ks * 32 + (lane >> 4) * 8);

  const int r = tid >> 1, half = tid & 1;
  const int t0 = tb * 128;
  const size_t qoff = (size_t)(n * T_ + t0 + r) * H_ + h * DH + half * 32;
  u16x8 qv[4];
#pragma unroll
  for (int s = 0; s < 4; ++s) qv[s] = *(const u16x8*)(Pq + qoff + s * 8);
  float e[32]; float sum = 0.f;
#pragma unroll
  for (int s = 0; s < 4; ++s)
#pragma unroll
    for (int j = 0; j < 8; ++j) { float x = __expf(bf2f(qv[s][j])); e[s * 8 + j] = x; sum += x; }
  sum += __shfl_xor(sum, 1);
  const float inv = 1.f / sum;
#pragma unroll
  for (int s = 0; s < 4; ++s) {
    u16x8 pb;
#pragma unroll
    for (int j = 0; j < 8; ++j) pb[j] = f2bf(e[s * 8 + j] * inv);
    *(u16x8*)&sp[r][half * 32 + s * 8] = pb;
  }
  __syncthreads();

  f32x4 acc[2][4];
  f32x4 z = {0.f, 0.f, 0.f, 0.f};
#pragma unroll
  for (int mm = 0; mm < 2; ++mm)
#pragma unroll
    for (int nn = 0; nn < 4; ++nn) acc[mm][nn] = z;
  const int wm = wid * 32;
#pragma unroll
  for (int ks = 0; ks < 2; ++ks) {
    bf16x8 av[2];
#pragma unroll
    for (int mm = 0; mm < 2; ++mm)
      av[mm] = *(const bf16x8*)((const char*)&sp[0][0]
               + (wm + mm * 16 + (lane & 15)) * 144 + ks * 64 + (lane >> 4) * 16);
#pragma unroll
    for (int mm = 0; mm < 2; ++mm)
#pragma unroll
      for (int nn = 0; nn < 4; ++nn)
        acc[mm][nn] = __builtin_amdgcn_mfma_f32_16x16x32_bf16(av[mm], breg[ks][nn], acc[mm][nn], 0, 0, 0);
  }

#pragma unroll
  for (int mm = 0; mm < 2; ++mm)
#pragma unroll
    for (int j = 0; j < 4; ++j) {
      const int row = t0 + wm + mm * 16 + (lane >> 4) * 4 + j;
      float* op = Out + ((size_t)n * T_ + row) * H_ + h * DH + (lane & 15);
#pragma unroll
      for (int nn = 0; nn < 4; ++nn) op[nn * 16] = acc[mm][nn][j];
    }
}

// ---------------------------------------------------------------- launch
extern "C" void kernel_launch(void* const* d_in, const int* in_sizes, int n_in,
                              void* d_out, int out_size, void* d_ws, size_t ws_size,
                              hipStream_t stream) {
  const float* q  = (const float*)d_in[0];
  const float* k  = (const float*)d_in[1];
  const float* v  = (const float*)d_in[2];
  // d_in[3] = mask_q: per-row constant before feature-dim softmax -> provably a no-op
  const float* mask_attn = (const float*)d_in[4];
  const float* Wq = (const float*)d_in[5];
  const float* bq = (const float*)d_in[6];
  const float* Wk = (const float*)d_in[7];
  const float* bk = (const float*)d_in[8];
  const float* Wv = (const float*)d_in[9];
  const float* bv = (const float*)d_in[10];
  float* out = (float*)d_out;

  char* ws = (char*)d_ws;
  size_t off = 0;
  unsigned short* Wb = (unsigned short*)(ws + off); off += (size_t)3 * H_ * H_ * 2;   // 6 MB
  unsigned short* Pq = (unsigned short*)(ws + off); off += (size_t)BT * H_ * 2;
  unsigned short* Pk = (unsigned short*)(ws + off); off += (size_t)BT * H_ * 2;
  unsigned short* Pv = (unsigned short*)(ws + off); off += (size_t)BT * H_ * 2;
  float* Upart  = (float*)(ws + off); off += (size_t)8 * 64 * 64 * 64 * 4;            // 8 MB
  float* cspart = (float*)(ws + off); off += (size_t)8 * 64 * 64 * 4;
  unsigned short* ctxT = (unsigned short*)(ws + off); off += (size_t)64 * 64 * 64 * 2;

  dim3 blk(256);
  const int nW4 = H_ * H_ / 4;
  cvt_kernel<<<dim3(512), blk, 0, stream>>>(Wq, Wb + 0 * H_ * H_, nW4);
  cvt_kernel<<<dim3(512), blk, 0, stream>>>(Wk, Wb + 1 * H_ * H_, nW4);
  cvt_kernel<<<dim3(512), blk, 0, stream>>>(Wv, Wb + 2 * H_ * H_, nW4);

  dim3 gblk(512);
  dim3 ggrid(512);   // 128 Mtiles x 4 Ntiles
  gemm256<<<ggrid, gblk, 0, stream>>>(k, Wb + 1 * H_ * H_, bk, Pk);
  gemm256<<<ggrid, gblk, 0, stream>>>(v, Wb + 2 * H_ * H_, bv, Pv);
  gemm256<<<ggrid, gblk, 0, stream>>>(q, Wb + 0 * H_ * H_, bq, Pq);

  phase1<<<dim3(8, 64), blk, 0, stream>>>(Pk, Pv, mask_attn, Upart, cspart);
  ctxbuild<<<dim3(64), blk, 0, stream>>>(Upart, cspart, ctxT);
  outk<<<dim3(64, 64), blk, 0, stream>>>(Pq, ctxT, out);
}

// Round 8
// 386.932 us; speedup vs baseline: 1.0766x; 1.0459x over previous
//
#include <hip/hip_runtime.h>
#include <hip/hip_bf16.h>
#include <math.h>

// Problem constants
#define B_  4
#define T_  8192
#define H_  1024
#define NHEAD 16
#define DH  64
#define BT  (B_*T_)   // 32768 rows

typedef __attribute__((ext_vector_type(8))) short bf16x8;
typedef __attribute__((ext_vector_type(4))) float f32x4;
typedef __attribute__((ext_vector_type(2))) float f32x2;
typedef __attribute__((ext_vector_type(2))) unsigned short u16x2;
typedef __attribute__((ext_vector_type(4))) unsigned short u16x4;
typedef __attribute__((ext_vector_type(8))) unsigned short u16x8;

static __device__ __forceinline__ float bf2f(unsigned short u) {
  union { unsigned int i; float f; } x; x.i = ((unsigned int)u) << 16; return x.f;
}
static __device__ __forceinline__ unsigned short f2bf(float f) {
  union { float f; unsigned int i; } x; x.f = f;
  unsigned int r = x.i + 0x7fffu + ((x.i >> 16) & 1u);  // RNE
  return (unsigned short)(r >> 16);
}

#define GL2LDS(gptr, sptr) \
  __builtin_amdgcn_global_load_lds((const __attribute__((address_space(1))) void*)(gptr), \
                                   (__attribute__((address_space(3))) void*)(sptr), 16, 0, 0)

#define BAR() do { asm volatile("" ::: "memory"); __builtin_amdgcn_s_barrier(); \
                   asm volatile("" ::: "memory"); } while (0)

// ---------------------------------------------------------------- cvt fp32->bf16 (weights only)
__global__ void cvt_kernel(const float* __restrict__ in, unsigned short* __restrict__ out, int n4) {
  int i = blockIdx.x * blockDim.x + threadIdx.x;
  int stride = gridDim.x * blockDim.x;
  for (int idx = i; idx < n4; idx += stride) {
    float4 v = reinterpret_cast<const float4*>(in)[idx];
    u16x4 o;
    o.x = f2bf(v.x); o.y = f2bf(v.y); o.z = f2bf(v.z); o.w = f2bf(v.w);
    reinterpret_cast<u16x4*>(out)[idx] = o;
  }
}

// ---------------------------------------------------------------- 256x256 bf16 GEMM, 2-barrier tile, fused fp32 A
// C[M,N] = cvt(A_f32)[M,K]*B[N,K]^T + bias ; M=32768, N=K=1024. BM=BN=256,
// BK=64, 8 waves (2M x 4N). LDS 128KB = 2 buffers (A 32KB + B 32KB each).
// Per K-tile (r8 restructure):
//  S1: read ALL bF (8xb128) + aF mh0 (8); burst0 (32 MFMA); read aF mh1 (8,
//      reusing aF regs); lgkmcnt(0); BAR   <- all reads of buf b complete.
//  S2: stB(t+2) DMA; burst1 (32 MFMA); vmcnt(4); writeA(tile t+2, cvt+4x
//      ds_write); issueA32(t+3) into single ar set (write-then-issue);
//      lgkmcnt(0); BAR.
// vmcnt invariant entering S1(t): B(t+1) 4 + A32(t+2) 8 = 12 (issue order in
// S2: stB then issueA32). S2(t): +stB 4 -> 16; vmcnt(4) drains B(t+1)
// [needed S1(t+1)] + A32(t+2) [needed writeA]; +issueA32 8 -> 12. Tails:
// t=13 no issue -> vmcnt(4) leaves B(15); t=14 vmcnt(0); t=15 nothing.
// Slack: A32 regs and B DMA each get one full tile (~2500 cyc).
// SWIZZLE (r5-verified, 0 conflicts): byte ^= ((row&7)<<4); A via swizzled
// ds_write addr; B via pre-swizzled global source + linear gload_lds dest.
// Registers: aF 32 + bF 32 + ar 32 + misc ~25 = ~121 VGPR + 128 acc <= 256.
// grid = 512 blocks, XCD-bijective swizzle (512%8==0).
__global__ __launch_bounds__(512, 2) void gemm256(
    const float* __restrict__ A,
    const unsigned short* __restrict__ Bm,
    const float* __restrict__ bias,
    unsigned short* __restrict__ C) {
  const int K = 1024, N = 1024;
  __shared__ char lds[131072];
  const int tid = threadIdx.x, lane = tid & 63, wid = tid >> 6;
  const int orig = blockIdx.x;
  const int swzb = (orig & 7) * 64 + (orig >> 3);
  const int bm = (swzb >> 2) * 256, bn = (swzb & 3) * 256;
  const int wm = wid >> 2, wn = wid & 3;

  // A fp32 reg-staging: thread covers 8 floats of row asr in 4 row-slots;
  // ds_write goes to the swizzled byte address.
  const int asr = wid * 8 + (lane >> 3);          // row 0..63 within slot
  const int ac0 = (lane & 7) * 8;                 // fp32 col within K-tile
  const float* gA32 = A + (size_t)(bm + asr) * K + ac0;
  const int awr = asr * 128 + (((lane & 7) * 16) ^ ((asr & 7) << 4));

  // B staging (gload_lds, pre-swizzled source)
  const int sr   = wid * 8 + (lane >> 3);
  const int scol = ((lane & 7) * 8) ^ ((lane >> 3) << 3);
  const unsigned short* gB = Bm + (size_t)(bn + sr) * K + scol;
  const int dstw = wid * 1024;

  // fragment read: col = ((lane>>4)*16 + ks*64) ^ ((lane&7)<<4)
  const int aswz  = (lane & 7) << 4;
  const int arow0 = (wm * 128 + (lane & 15)) * 128;            // A row-base bytes
  const int brow0 = 32768 + (wn * 64 + (lane & 15)) * 128;     // B row-base bytes

  f32x4 acc[8][4];
#pragma unroll
  for (int fn = 0; fn < 4; ++fn) {
    float bv = bias[bn + wn * 64 + fn * 16 + (lane & 15)];
    f32x4 sp = {bv, bv, bv, bv};
#pragma unroll
    for (int fm = 0; fm < 8; ++fm) acc[fm][fn] = sp;
  }

  bf16x8 aF[4][2], bF[4][2];
  f32x4 ar[4][2];   // single in-flight A fp32 set (32 VGPRs)

  auto issueA32 = [&](int kt) {
#pragma unroll
    for (int s = 0; s < 4; ++s) {
      const float* g = gA32 + (size_t)(s * 64) * K + kt * 64;
      ar[s][0] = *(const f32x4*)(g);
      ar[s][1] = *(const f32x4*)(g + 4);
    }
  };
  auto writeA = [&](int buf) {
#pragma unroll
    for (int s = 0; s < 4; ++s) {
      u16x8 o;
#pragma unroll
      for (int j = 0; j < 4; ++j) { o[j] = (short)f2bf(ar[s][0][j]); o[4 + j] = (short)f2bf(ar[s][1][j]); }
      *(u16x8*)(lds + buf * 65536 + s * 8192 + awr) = o;
    }
  };
  auto stB = [&](int buf, int kt) {                  // full B tile: 4 gloads
    char* d = lds + buf * 65536 + 32768 + dstw;
    const unsigned short* g = gB + kt * 64;
    GL2LDS(g, d);
    GL2LDS(g + (size_t)64  * K, d + 8192);
    GL2LDS(g + (size_t)128 * K, d + 16384);
    GL2LDS(g + (size_t)192 * K, d + 24576);
  };
  auto loadA = [&](int buf, int mh) {
#pragma unroll
    for (int f = 0; f < 4; ++f)
#pragma unroll
      for (int ks = 0; ks < 2; ++ks)
        aF[f][ks] = *(const bf16x8*)(lds + buf * 65536 + arow0 + (mh * 4 + f) * 2048
                                     + (((lane >> 4) * 16 + ks * 64) ^ aswz));
  };
  auto loadBall = [&](int buf) {
#pragma unroll
    for (int fn = 0; fn < 4; ++fn)
#pragma unroll
      for (int ks = 0; ks < 2; ++ks)
        bF[fn][ks] = *(const bf16x8*)(lds + buf * 65536 + brow0 + fn * 2048
                                      + (((lane >> 4) * 16 + ks * 64) ^ aswz));
  };
  auto burst = [&](int mh) {                         // 32 MFMA cluster (T5 setprio)
    __builtin_amdgcn_s_setprio(1);
#pragma unroll
    for (int f = 0; f < 4; ++f)
#pragma unroll
      for (int fn = 0; fn < 4; ++fn)
#pragma unroll
        for (int ks = 0; ks < 2; ++ks)
          acc[mh * 4 + f][fn] = __builtin_amdgcn_mfma_f32_16x16x32_bf16(
              aF[f][ks], bF[fn][ks], acc[mh * 4 + f][fn], 0, 0, 0);
    __builtin_amdgcn_s_setprio(0);
  };

  // prologue: A tiles 0,1 via reg+ds_write; B tiles 0,1 via gload_lds; ar <- tile2
  issueA32(0);
  asm volatile("s_waitcnt vmcnt(0)" ::: "memory");
  writeA(0);
  issueA32(1);
  asm volatile("s_waitcnt vmcnt(0)" ::: "memory");
  writeA(1);
  stB(0, 0); stB(1, 1);
  issueA32(2);
  asm volatile("s_waitcnt vmcnt(12)" ::: "memory");  // drains B(0); leaves B(1)+A32(2)=12
  asm volatile("s_waitcnt lgkmcnt(0)" ::: "memory");
  BAR();

#define KTILE(t, STB_, DOW, WSTR, DOWRITE, DOISSUE)           \
  {                                                           \
    const int b_ = (t) & 1;                                   \
    loadBall(b_);                                             \
    loadA(b_, 0);                                             \
    burst(0);                                                 \
    loadA(b_, 1);                                             \
    asm volatile("s_waitcnt lgkmcnt(0)" ::: "memory");        \
    BAR();                                                    \
    if (STB_) stB(b_, (t) + 2);                               \
    burst(1);                                                 \
    if (DOW) { asm volatile("s_waitcnt vmcnt(" WSTR ")" ::: "memory"); } \
    if (DOWRITE) writeA(b_);                                  \
    if (DOISSUE) issueA32((t) + 3);                           \
    asm volatile("s_waitcnt lgkmcnt(0)" ::: "memory");        \
    BAR();                                                    \
  }

  for (int t = 0; t < 13; ++t) KTILE(t, 1, 1, "4", 1, 1)
  KTILE(13, 1, 1, "4", 1, 0)
  KTILE(14, 0, 1, "0", 0, 0)
  KTILE(15, 0, 0, "0", 0, 0)
#undef KTILE

  // epilogue: C write
  const int crow0 = bm + wm * 128 + (lane >> 4) * 4;
  const int ccol0 = bn + wn * 64 + (lane & 15);
#pragma unroll
  for (int fm = 0; fm < 8; ++fm)
#pragma unroll
    for (int j = 0; j < 4; ++j) {
      unsigned short* cp = C + (size_t)(crow0 + fm * 16 + j) * N + ccol0;
#pragma unroll
      for (int fn = 0; fn < 4; ++fn) cp[fn * 16] = f2bf(acc[fm][fn][j]);
    }
}

// ---------------------------------------------------------------- phase1 (MFMA): U-partials + colsum
__global__ __launch_bounds__(256, 2) void phase1(
    const unsigned short* __restrict__ Pk,
    const unsigned short* __restrict__ Pv,
    const float* __restrict__ mask_attn,
    float* __restrict__ Upart,     // [8][64][64][64]
    float* __restrict__ cspart) {  // [8][64][64]
  const int chunk = blockIdx.x;
  const int nh = blockIdx.y;
  const int n = nh >> 4, h = nh & 15;
  const int tid = threadIdx.x, lane = tid & 63, wid = tid >> 6;
  __shared__ __align__(16) unsigned short ekT[64 * 256];  // 32 KB
  __shared__ __align__(16) unsigned short vpT[64 * 256];  // 32 KB

  f32x4 acc[5];
#pragma unroll
  for (int i = 0; i < 5; ++i) acc[i] = (f32x4){0.f, 0.f, 0.f, 0.f};
  bf16x8 ones;
#pragma unroll
  for (int j = 0; j < 8; ++j) ones[j] = (short)0x3f80;

  const int isV = tid >> 7;
  const int slot0 = tid & 127;
  const unsigned short* src = isV ? Pv : Pk;
  unsigned short* dstT = isV ? vpT : ekT;

  const int arow = wid * 16 + (lane & 15);
  const int aswz = ((arow & 7) ^ ((arow >> 3) & 7)) << 4;

  for (int stage = 0; stage < 4; ++stage) {
    if (stage) __syncthreads();
#pragma unroll
    for (int r = 0; r < 2; ++r) {
      const int slot = slot0 + r * 128;
      const int toct = slot >> 3;
      const int d0   = (slot & 7) * 8;
      const int tbase = chunk * 1024 + stage * 256 + toct * 8;
      u16x8 in[8];
#pragma unroll
      for (int s = 0; s < 8; ++s)
        in[s] = *(const u16x8*)(src + (size_t)(n * T_ + tbase + s) * H_ + h * DH + d0);
      if (!isV) {
#pragma unroll
        for (int s = 0; s < 8; ++s) {
          const float madd = -10000.f * (1.f - mask_attn[n * T_ + tbase + s]);
          u16x8 o;
#pragma unroll
          for (int j = 0; j < 8; ++j) o[j] = f2bf(__expf(bf2f(in[s][j]) + madd));
          in[s] = o;
        }
      }
#pragma unroll
      for (int i = 0; i < 8; ++i) {
        u16x8 o;
#pragma unroll
        for (int s = 0; s < 8; ++s) o[s] = in[s][i];
        const int d = d0 + i;
        const int boff = (toct * 16) ^ (((d & 7) ^ ((d >> 3) & 7)) << 4);
        *(u16x8*)((char*)dstT + d * 512 + boff) = o;
      }
    }
    __syncthreads();
#pragma unroll
    for (int kk = 0; kk < 8; ++kk) {
      const int koff = kk * 64 + (lane >> 4) * 16;
      bf16x8 af = *(const bf16x8*)((const char*)ekT + arow * 512 + (koff ^ aswz));
      acc[4] = __builtin_amdgcn_mfma_f32_16x16x32_bf16(af, ones, acc[4], 0, 0, 0);
#pragma unroll
      for (int nn = 0; nn < 4; ++nn) {
        const int brow = nn * 16 + (lane & 15);
        const int bswz = ((brow & 7) ^ ((brow >> 3) & 7)) << 4;
        bf16x8 bf_ = *(const bf16x8*)((const char*)vpT + brow * 512 + (koff ^ bswz));
        acc[nn] = __builtin_amdgcn_mfma_f32_16x16x32_bf16(af, bf_, acc[nn], 0, 0, 0);
      }
    }
  }

  const int d = wid * 16 + (lane >> 4) * 4;
  const int e = lane & 15;
  float* up = Upart + ((size_t)(chunk * 64 + nh) * 64) * 64;
#pragma unroll
  for (int nn = 0; nn < 4; ++nn)
#pragma unroll
    for (int j = 0; j < 4; ++j)
      up[(size_t)(d + j) * 64 + nn * 16 + e] = acc[nn][j];
  if (e == 0)
#pragma unroll
    for (int j = 0; j < 4; ++j)
      cspart[((size_t)chunk * 64 + nh) * 64 + d + j] = acc[4][j];
}

// ---------------------------------------------------------------- ctx build
__global__ void ctxbuild(const float* __restrict__ Upart,
                         const float* __restrict__ cspart,
                         unsigned short* __restrict__ ctxT) {  // [64 nh][64 e][64 d]
  const int nh = blockIdx.x, tid = threadIdx.x;
  __shared__ float cs[64];
  if (tid < 64) {
    float s = 0;
    for (int c = 0; c < 8; ++c) s += cspart[((size_t)c * 64 + nh) * 64 + tid];
    cs[tid] = s;
  }
  __syncthreads();
  const int d0 = (tid >> 4) * 4, e0 = (tid & 15) * 4;
#pragma unroll
  for (int i = 0; i < 4; ++i) {
    const float inv = 0.125f / cs[d0 + i];   // 1/(sqrt(64)*colsum)
#pragma unroll
    for (int j = 0; j < 4; ++j) {
      float s = 0;
      for (int c = 0; c < 8; ++c)
        s += Upart[((size_t)(c * 64 + nh) * 64 + d0 + i) * 64 + e0 + j];
      ctxT[((size_t)nh * 64 + (e0 + j)) * 64 + (d0 + i)] = f2bf(s * inv);
    }
  }
}

// ---------------------------------------------------------------- out: softmax_feat(qp) @ ctx
__global__ __launch_bounds__(256) void outk(
    const unsigned short* __restrict__ Pq,
    const unsigned short* __restrict__ ctxT,
    float* __restrict__ Out) {
  const int tb = blockIdx.x;
  const int nh = blockIdx.y;
  const int n = nh >> 4, h = nh & 15;
  const int tid = threadIdx.x, lane = tid & 63, wid = tid >> 6;
  __shared__ unsigned short sp[128][72];

  bf16x8 breg[2][4];
#pragma unroll
  for (int ks = 0; ks < 2; ++ks)
#pragma unroll
    for (int nn = 0; nn < 4; ++nn)
      breg[ks][nn] = *(const bf16x8*)(ctxT + ((size_t)nh * 64 + nn * 16 + (lane & 15)) * 64
                                      + ks * 32 + (lane >> 4) * 8);

  const int r = tid >> 1, half = tid & 1;
  const int t0 = tb * 128;
  const size_t qoff = (size_t)(n * T_ + t0 + r) * H_ + h * DH + half * 32;
  u16x8 qv[4];
#pragma unroll
  for (int s = 0; s < 4; ++s) qv[s] = *(const u16x8*)(Pq + qoff + s * 8);
  float e[32]; float sum = 0.f;
#pragma unroll
  for (int s = 0; s < 4; ++s)
#pragma unroll
    for (int j = 0; j < 8; ++j) { float x = __expf(bf2f(qv[s][j])); e[s * 8 + j] = x; sum += x; }
  sum += __shfl_xor(sum, 1);
  const float inv = 1.f / sum;
#pragma unroll
  for (int s = 0; s < 4; ++s) {
    u16x8 pb;
#pragma unroll
    for (int j = 0; j < 8; ++j) pb[j] = f2bf(e[s * 8 + j] * inv);
    *(u16x8*)&sp[r][half * 32 + s * 8] = pb;
  }
  __syncthreads();

  f32x4 acc[2][4];
  f32x4 z = {0.f, 0.f, 0.f, 0.f};
#pragma unroll
  for (int mm = 0; mm < 2; ++mm)
#pragma unroll
    for (int nn = 0; nn < 4; ++nn) acc[mm][nn] = z;
  const int wm = wid * 32;
#pragma unroll
  for (int ks = 0; ks < 2; ++ks) {
    bf16x8 av[2];
#pragma unroll
    for (int mm = 0; mm < 2; ++mm)
      av[mm] = *(const bf16x8*)((const char*)&sp[0][0]
               + (wm + mm * 16 + (lane & 15)) * 144 + ks * 64 + (lane >> 4) * 16);
#pragma unroll
    for (int mm = 0; mm < 2; ++mm)
#pragma unroll
      for (int nn = 0; nn < 4; ++nn)
        acc[mm][nn] = __builtin_amdgcn_mfma_f32_16x16x32_bf16(av[mm], breg[ks][nn], acc[mm][nn], 0, 0, 0);
  }

#pragma unroll
  for (int mm = 0; mm < 2; ++mm)
#pragma unroll
    for (int j = 0; j < 4; ++j) {
      const int row = t0 + wm + mm * 16 + (lane >> 4) * 4 + j;
      float* op = Out + ((size_t)n * T_ + row) * H_ + h * DH + (lane & 15);
#pragma unroll
      for (int nn = 0; nn < 4; ++nn) op[nn * 16] = acc[mm][nn][j];
    }
}

// ---------------------------------------------------------------- launch
extern "C" void kernel_launch(void* const* d_in, const int* in_sizes, int n_in,
                              void* d_out, int out_size, void* d_ws, size_t ws_size,
                              hipStream_t stream) {
  const float* q  = (const float*)d_in[0];
  const float* k  = (const float*)d_in[1];
  const float* v  = (const float*)d_in[2];
  // d_in[3] = mask_q: per-row constant before feature-dim softmax -> provably a no-op
  const float* mask_attn = (const float*)d_in[4];
  const float* Wq = (const float*)d_in[5];
  const float* bq = (const float*)d_in[6];
  const float* Wk = (const float*)d_in[7];
  const float* bk = (const float*)d_in[8];
  const float* Wv = (const float*)d_in[9];
  const float* bv = (const float*)d_in[10];
  float* out = (float*)d_out;

  char* ws = (char*)d_ws;
  size_t off = 0;
  unsigned short* Wb = (unsigned short*)(ws + off); off += (size_t)3 * H_ * H_ * 2;   // 6 MB
  unsigned short* Pq = (unsigned short*)(ws + off); off += (size_t)BT * H_ * 2;
  unsigned short* Pk = (unsigned short*)(ws + off); off += (size_t)BT * H_ * 2;
  unsigned short* Pv = (unsigned short*)(ws + off); off += (size_t)BT * H_ * 2;
  float* Upart  = (float*)(ws + off); off += (size_t)8 * 64 * 64 * 64 * 4;            // 8 MB
  float* cspart = (float*)(ws + off); off += (size_t)8 * 64 * 64 * 4;
  unsigned short* ctxT = (unsigned short*)(ws + off); off += (size_t)64 * 64 * 64 * 2;

  dim3 blk(256);
  const int nW4 = H_ * H_ / 4;
  cvt_kernel<<<dim3(512), blk, 0, stream>>>(Wq, Wb + 0 * H_ * H_, nW4);
  cvt_kernel<<<dim3(512), blk, 0, stream>>>(Wk, Wb + 1 * H_ * H_, nW4);
  cvt_kernel<<<dim3(512), blk, 0, stream>>>(Wv, Wb + 2 * H_ * H_, nW4);

  dim3 gblk(512);
  dim3 ggrid(512);   // 128 Mtiles x 4 Ntiles
  gemm256<<<ggrid, gblk, 0, stream>>>(k, Wb + 1 * H_ * H_, bk, Pk);
  gemm256<<<ggrid, gblk, 0, stream>>>(v, Wb + 2 * H_ * H_, bv, Pv);
  gemm256<<<ggrid, gblk, 0, stream>>>(q, Wb + 0 * H_ * H_, bq, Pq);

  phase1<<<dim3(8, 64), blk, 0, stream>>>(Pk, Pv, mask_attn, Upart, cspart);
  ctxbuild<<<dim3(64), blk, 0, stream>>>(Upart, cspart, ctxT);
  outk<<<dim3(64, 64), blk, 0, stream>>>(Pq, ctxT, out);
}